// Round 1
// baseline (125.954 us; speedup 1.0000x reference)
//
#include <hip/hip_runtime.h>
#include <hip/hip_bf16.h>

// Co-attention layer:
//   emb[l,e] = x[l]*emb_W[l,e] + emb_b[l,e]
//   G[l,r]   = tanh( left[l,:] @ M @ right[r,:]^T ),  left=emb[0:16], right=emb[16:32]
//   lr = softmax_r( sum_l G[l,r] ),  rl = softmax_l( sum_r G[l,r] )
//   a  = [lr, rl];  out = relu( (x*a) @ dense_W + dense_b )
// One thread per batch element. All weights are wave-uniform -> scalar loads.

#if __has_builtin(__builtin_amdgcn_exp2f)
#define EXP2F(v) __builtin_amdgcn_exp2f(v)
#else
#define EXP2F(v) exp2f(v)
#endif

#if __has_builtin(__builtin_amdgcn_rcpf)
#define RCPF(v) __builtin_amdgcn_rcpf(v)
#else
#define RCPF(v) (1.0f / (v))
#endif

#define LOG2E 1.4426950408889634f

__device__ __forceinline__ float fast_tanh(float v) {
    // tanh(v) = 1 - 2/(exp(2v)+1); exp(2v) = 2^(2*log2(e)*v)
    float E = EXP2F(v * (2.0f * LOG2E));
    return 1.0f - 2.0f * RCPF(E + 1.0f);
}

__global__ __launch_bounds__(256) void coattn_kernel(
    const float* __restrict__ x,
    const float* __restrict__ emb_W,
    const float* __restrict__ emb_b,
    const float* __restrict__ M,
    const float* __restrict__ dW,
    const float* __restrict__ db,
    float* __restrict__ out)
{
    const int i = blockIdx.x * blockDim.x + threadIdx.x;

    // ---- load x[32] (coalesced float4) ----
    float xv[32];
    const float4* xp = reinterpret_cast<const float4*>(x + (size_t)i * 32);
    #pragma unroll
    for (int k = 0; k < 8; ++k) {
        float4 v = xp[k];
        xv[4*k+0] = v.x; xv[4*k+1] = v.y; xv[4*k+2] = v.z; xv[4*k+3] = v.w;
    }

    // ---- MR[r][e] = sum_f M[e][f] * right[r][f] ----
    float MR[16][8];
    #pragma unroll
    for (int r = 0; r < 16; ++r) {
        float re[8];
        #pragma unroll
        for (int f = 0; f < 8; ++f)
            re[f] = fmaf(xv[16 + r], emb_W[(16 + r) * 8 + f], emb_b[(16 + r) * 8 + f]);
        #pragma unroll
        for (int e = 0; e < 8; ++e) {
            float acc = M[e * 8 + 0] * re[0];
            #pragma unroll
            for (int f = 1; f < 8; ++f)
                acc = fmaf(M[e * 8 + f], re[f], acc);
            MR[r][e] = acc;
        }
    }

    // ---- G[l,r] = tanh(dot8(left[l], MR[r])); accumulate row/col sums ----
    float colsum[16], rowsum[16];
    #pragma unroll
    for (int r = 0; r < 16; ++r) colsum[r] = 0.0f;

    #pragma unroll
    for (int l = 0; l < 16; ++l) {
        float le[8];
        #pragma unroll
        for (int e = 0; e < 8; ++e)
            le[e] = fmaf(xv[l], emb_W[l * 8 + e], emb_b[l * 8 + e]);
        float rs = 0.0f;
        #pragma unroll
        for (int r = 0; r < 16; ++r) {
            float g = le[0] * MR[r][0];
            #pragma unroll
            for (int e = 1; e < 8; ++e)
                g = fmaf(le[e], MR[r][e], g);
            float t = fast_tanh(g);
            rs += t;
            colsum[r] += t;
        }
        rowsum[l] = rs;
    }

    // ---- a[0:16] = softmax(colsum), a[16:32] = softmax(rowsum) ----
    // |sum| <= 16 so exp stays finite in f32 without max-subtraction.
    float a[32];
    {
        float s = 0.0f;
        #pragma unroll
        for (int r = 0; r < 16; ++r) {
            float e = EXP2F(colsum[r] * LOG2E);
            a[r] = e; s += e;
        }
        float inv = RCPF(s);
        #pragma unroll
        for (int r = 0; r < 16; ++r) a[r] *= inv;
    }
    {
        float s = 0.0f;
        #pragma unroll
        for (int l = 0; l < 16; ++l) {
            float e = EXP2F(rowsum[l] * LOG2E);
            a[16 + l] = e; s += e;
        }
        float inv = RCPF(s);
        #pragma unroll
        for (int l = 0; l < 16; ++l) a[16 + l] *= inv;
    }

    // ---- out = relu( (x*a) @ dW + db ) ----
    float o[16];
    #pragma unroll
    for (int k = 0; k < 16; ++k) o[k] = db[k];
    #pragma unroll
    for (int j = 0; j < 32; ++j) {
        float v = xv[j] * a[j];
        #pragma unroll
        for (int k = 0; k < 16; ++k)
            o[k] = fmaf(v, dW[j * 16 + k], o[k]);
    }

    float4* op = reinterpret_cast<float4*>(out + (size_t)i * 16);
    #pragma unroll
    for (int k = 0; k < 4; ++k) {
        float4 v;
        v.x = fmaxf(o[4*k+0], 0.0f);
        v.y = fmaxf(o[4*k+1], 0.0f);
        v.z = fmaxf(o[4*k+2], 0.0f);
        v.w = fmaxf(o[4*k+3], 0.0f);
        op[k] = v;
    }
}

extern "C" void kernel_launch(void* const* d_in, const int* in_sizes, int n_in,
                              void* d_out, int out_size, void* d_ws, size_t ws_size,
                              hipStream_t stream) {
    const float* x     = (const float*)d_in[0];
    const float* emb_W = (const float*)d_in[1];
    const float* emb_b = (const float*)d_in[2];
    const float* M     = (const float*)d_in[3];
    const float* dW    = (const float*)d_in[4];
    const float* db    = (const float*)d_in[5];
    float* out = (float*)d_out;

    const int B = in_sizes[0] / 32;
    dim3 block(256);
    dim3 grid((B + 255) / 256);
    hipLaunchKernelGGL(coattn_kernel, grid, block, 0, stream,
                       x, emb_W, emb_b, M, dW, db, out);
}

// Round 2
// 110.769 us; speedup vs baseline: 1.1371x; 1.1371x over previous
//
#include <hip/hip_runtime.h>
#include <hip/hip_bf16.h>

// Co-attention layer, factorized form.
// emb is affine in x, so the pre-tanh score factorizes:
//   G_pre[l,r] = x_l*x_r*C1[l,r] + x_l*C2[l,r] + x_r*C3[l,r] + C4[l,r]
// with C1=W_l·(M·W_r), C2=W_l·(M·b_r), C3=b_l·(M·W_r), C4=b_l·(M·b_r)
// (weight-only 16x16 constants, precomputed per launch into d_ws,
//  pre-scaled by 2*log2(e) so tanh(g) = 1 - 2/(exp2(g')+1) directly).

#if __has_builtin(__builtin_amdgcn_exp2f)
#define EXP2F(v) __builtin_amdgcn_exp2f(v)
#else
#define EXP2F(v) exp2f(v)
#endif

#if __has_builtin(__builtin_amdgcn_rcpf)
#define RCPF(v) __builtin_amdgcn_rcpf(v)
#else
#define RCPF(v) (1.0f / (v))
#endif

#define LOG2E 1.4426950408889634f

// ---------------- setup: C1..C4 (4 x 16 x 16 floats) into d_ws ----------------
__global__ __launch_bounds__(256) void coattn_setup(
    const float* __restrict__ emb_W,
    const float* __restrict__ emb_b,
    const float* __restrict__ M,
    float* __restrict__ C)
{
    const int t = threadIdx.x;          // one thread per (l, r) pair
    const int l = t >> 4;
    const int r = t & 15;

    // MW[e] = sum_f M[e][f] * emb_W[16+r][f];  Mb[e] likewise with emb_b
    float MW[8], Mb[8];
    #pragma unroll
    for (int e = 0; e < 8; ++e) {
        float s1 = 0.0f, s2 = 0.0f;
        #pragma unroll
        for (int f = 0; f < 8; ++f) {
            float m = M[e * 8 + f];
            s1 = fmaf(m, emb_W[(16 + r) * 8 + f], s1);
            s2 = fmaf(m, emb_b[(16 + r) * 8 + f], s2);
        }
        MW[e] = s1; Mb[e] = s2;
    }
    float c1 = 0.0f, c2 = 0.0f, c3 = 0.0f, c4 = 0.0f;
    #pragma unroll
    for (int e = 0; e < 8; ++e) {
        float w = emb_W[l * 8 + e];
        float b = emb_b[l * 8 + e];
        c1 = fmaf(w, MW[e], c1);
        c2 = fmaf(w, Mb[e], c2);
        c3 = fmaf(b, MW[e], c3);
        c4 = fmaf(b, Mb[e], c4);
    }
    const float s = 2.0f * LOG2E;       // fold tanh's exp2 argument scale
    C[0 * 256 + l * 16 + r] = c1 * s;
    C[1 * 256 + l * 16 + r] = c2 * s;
    C[2 * 256 + l * 16 + r] = c3 * s;
    C[3 * 256 + l * 16 + r] = c4 * s;
}

// ---------------- main: one thread per batch element ----------------
__global__ __launch_bounds__(256) void coattn_kernel(
    const float* __restrict__ x,
    const float* __restrict__ C,      // C1..C4, each 256 floats, row-major [l][r]
    const float* __restrict__ dW,
    const float* __restrict__ db,
    float* __restrict__ out)
{
    const int i = blockIdx.x * blockDim.x + threadIdx.x;

    // ---- load x[32] (coalesced float4) ----
    float xv[32];
    const float4* xp = reinterpret_cast<const float4*>(x + (size_t)i * 32);
    #pragma unroll
    for (int k = 0; k < 8; ++k) {
        float4 v = xp[k];
        xv[4*k+0] = v.x; xv[4*k+1] = v.y; xv[4*k+2] = v.z; xv[4*k+3] = v.w;
    }

    // ---- G[l,r] = tanh(g') = 1 - 2*rcp(exp2(g')+1); accumulate row/col sums ----
    // Init accumulators at +16 so the per-pair "+1" of tanh is free.
    float colsum[16];
    #pragma unroll
    for (int r = 0; r < 16; ++r) colsum[r] = 16.0f;
    float rowsum[16];

    #pragma unroll
    for (int l = 0; l < 16; ++l) {
        const float xl = xv[l];
        float rs = 16.0f;
        #pragma unroll
        for (int r = 0; r < 16; ++r) {
            const float xr = xv[16 + r];
            // split fma into mul+add: each VALU op reads <=1 SGPR constant
            float u  = xr * C[0 * 256 + l * 16 + r] + C[1 * 256 + l * 16 + r];
            float v2 = xr * C[2 * 256 + l * 16 + r] + C[3 * 256 + l * 16 + r];
            float g  = fmaf(xl, u, v2);              // already scaled by 2*log2e
            float rc = RCPF(EXP2F(g) + 1.0f);
            rs         = fmaf(-2.0f, rc, rs);        // += tanh - 1
            colsum[r]  = fmaf(-2.0f, rc, colsum[r]);
        }
        rowsum[l] = rs;
    }

    // ---- a[0:16] = softmax(colsum), a[16:32] = softmax(rowsum) ----
    float a[32];
    {
        float s = 0.0f;
        #pragma unroll
        for (int r = 0; r < 16; ++r) {
            float e = EXP2F(colsum[r] * LOG2E);
            a[r] = e; s += e;
        }
        float inv = RCPF(s);
        #pragma unroll
        for (int r = 0; r < 16; ++r) a[r] *= inv;
    }
    {
        float s = 0.0f;
        #pragma unroll
        for (int l = 0; l < 16; ++l) {
            float e = EXP2F(rowsum[l] * LOG2E);
            a[16 + l] = e; s += e;
        }
        float inv = RCPF(s);
        #pragma unroll
        for (int l = 0; l < 16; ++l) a[16 + l] *= inv;
    }

    // ---- out = relu( (x*a) @ dW + db ) ----
    float o[16];
    #pragma unroll
    for (int k = 0; k < 16; ++k) o[k] = db[k];
    #pragma unroll
    for (int j = 0; j < 32; ++j) {
        float v = xv[j] * a[j];
        #pragma unroll
        for (int k = 0; k < 16; ++k)
            o[k] = fmaf(v, dW[j * 16 + k], o[k]);
    }

    float4* op = reinterpret_cast<float4*>(out + (size_t)i * 16);
    #pragma unroll
    for (int k = 0; k < 4; ++k) {
        float4 v;
        v.x = fmaxf(o[4*k+0], 0.0f);
        v.y = fmaxf(o[4*k+1], 0.0f);
        v.z = fmaxf(o[4*k+2], 0.0f);
        v.w = fmaxf(o[4*k+3], 0.0f);
        op[k] = v;
    }
}

extern "C" void kernel_launch(void* const* d_in, const int* in_sizes, int n_in,
                              void* d_out, int out_size, void* d_ws, size_t ws_size,
                              hipStream_t stream) {
    const float* x     = (const float*)d_in[0];
    const float* emb_W = (const float*)d_in[1];
    const float* emb_b = (const float*)d_in[2];
    const float* M     = (const float*)d_in[3];
    const float* dW    = (const float*)d_in[4];
    const float* db    = (const float*)d_in[5];
    float* out = (float*)d_out;
    float* C   = (float*)d_ws;          // 4 * 256 floats = 4 KB

    hipLaunchKernelGGL(coattn_setup, dim3(1), dim3(256), 0, stream,
                       emb_W, emb_b, M, C);

    const int B = in_sizes[0] / 32;
    dim3 block(256);
    dim3 grid((B + 255) / 256);
    hipLaunchKernelGGL(coattn_kernel, grid, block, 0, stream,
                       x, C, dW, db, out);
}

// Round 3
// 104.721 us; speedup vs baseline: 1.2028x; 1.0578x over previous
//
#include <hip/hip_runtime.h>
#include <hip/hip_bf16.h>

// Co-attention layer, factorized + f32-packed (VOP3P) form.
//   G_pre[l,r] = x_l*x_r*C1[l,r] + x_l*C2[l,r] + x_r*C3[l,r] + C4[l,r]
//   (C1..C4 weight-only, precomputed, pre-scaled by 2*log2e)
//   tanh(g) = 1 - 2*rcp(exp2(g')+1); softmax is shift-invariant, so only
//   S = sum rcp(...) is accumulated and softmax arg = -2*log2e * S.
// r processed in pairs -> v_pk_*_f32; SGPR constants read as aligned pairs.

typedef __attribute__((ext_vector_type(2))) float v2f;

#if __has_builtin(__builtin_amdgcn_exp2f)
#define EXP2F(v) __builtin_amdgcn_exp2f(v)
#else
#define EXP2F(v) exp2f(v)
#endif

#if __has_builtin(__builtin_amdgcn_rcpf)
#define RCPF(v) __builtin_amdgcn_rcpf(v)
#else
#define RCPF(v) (1.0f / (v))
#endif

#define LOG2E 1.4426950408889634f

__device__ __forceinline__ v2f fma2(v2f a, v2f b, v2f c) {
    return __builtin_elementwise_fma(a, b, c);
}

// ---------------- setup: C1..C4 (4 x 16 x 16 floats) into d_ws ----------------
__global__ __launch_bounds__(256) void coattn_setup(
    const float* __restrict__ emb_W,
    const float* __restrict__ emb_b,
    const float* __restrict__ M,
    float* __restrict__ C)
{
    const int t = threadIdx.x;          // one thread per (l, r) pair
    const int l = t >> 4;
    const int r = t & 15;

    float MW[8], Mb[8];
    #pragma unroll
    for (int e = 0; e < 8; ++e) {
        float s1 = 0.0f, s2 = 0.0f;
        #pragma unroll
        for (int f = 0; f < 8; ++f) {
            float m = M[e * 8 + f];
            s1 = fmaf(m, emb_W[(16 + r) * 8 + f], s1);
            s2 = fmaf(m, emb_b[(16 + r) * 8 + f], s2);
        }
        MW[e] = s1; Mb[e] = s2;
    }
    float c1 = 0.0f, c2 = 0.0f, c3 = 0.0f, c4 = 0.0f;
    #pragma unroll
    for (int e = 0; e < 8; ++e) {
        float w = emb_W[l * 8 + e];
        float b = emb_b[l * 8 + e];
        c1 = fmaf(w, MW[e], c1);
        c2 = fmaf(w, Mb[e], c2);
        c3 = fmaf(b, MW[e], c3);
        c4 = fmaf(b, Mb[e], c4);
    }
    const float s = 2.0f * LOG2E;       // fold tanh's exp2 argument scale
    C[0 * 256 + l * 16 + r] = c1 * s;
    C[1 * 256 + l * 16 + r] = c2 * s;
    C[2 * 256 + l * 16 + r] = c3 * s;
    C[3 * 256 + l * 16 + r] = c4 * s;
}

// ---------------- main: one thread per batch element ----------------
__global__ __launch_bounds__(256) void coattn_kernel(
    const float* __restrict__ x,
    const float* __restrict__ C,
    const float* __restrict__ dW,
    const float* __restrict__ db,
    float* __restrict__ out)
{
    // Keep scalar mul+add(SGPR) un-fused: a contracted fma would read two
    // SGPR constants (constant-bus limit 1) forcing v_mov materialization.
    #pragma clang fp contract(off)

    const int i = blockIdx.x * blockDim.x + threadIdx.x;

    // ---- load x[32] as float2 pairs ----
    v2f xv2[16];
    const float4* xp = reinterpret_cast<const float4*>(x + (size_t)i * 32);
    #pragma unroll
    for (int k = 0; k < 8; ++k) {
        float4 v = xp[k];
        xv2[2*k+0] = (v2f){v.x, v.y};
        xv2[2*k+1] = (v2f){v.z, v.w};
    }

    const v2f* C1 = reinterpret_cast<const v2f*>(C);        // [16][8] pairs
    const v2f* C2 = C1 + 128;
    const v2f* C3 = C2 + 128;
    const v2f* C4 = C3 + 128;

    // ---- accumulate S_col[r] = sum_l rc, S_row[l] = sum_r rc ----
    v2f Scol[8];
    #pragma unroll
    for (int k = 0; k < 8; ++k) Scol[k] = (v2f){0.0f, 0.0f};
    float Srow[16];

    #pragma unroll
    for (int l = 0; l < 16; ++l) {
        const float xl = xv2[l >> 1][l & 1];
        const v2f xl2 = (v2f){xl, xl};
        v2f rs = (v2f){0.0f, 0.0f};
        #pragma unroll
        for (int k = 0; k < 8; ++k) {
            const v2f xr2 = xv2[8 + k];
            v2f u = xl2 * C1[l * 8 + k];      // pk_mul (1 sgpr-pair)
            u = u + C3[l * 8 + k];            // pk_add (1 sgpr-pair)
            v2f w = xl2 * C2[l * 8 + k];      // pk_mul
            w = w + C4[l * 8 + k];            // pk_add
            v2f g = fma2(xr2, u, w);          // pk_fma (all VGPR)
            v2f E;
            E.x = EXP2F(g.x);
            E.y = EXP2F(g.y);
            v2f D = E + 1.0f;                 // pk_add (inline 1.0)
            v2f rc;
            rc.x = RCPF(D.x);
            rc.y = RCPF(D.y);
            Scol[k] = Scol[k] + rc;
            rs = rs + rc;
        }
        Srow[l] = rs.x + rs.y;
    }

    // ---- softmax (shift-invariant: arg = -2*log2e * S) ----
    const float NSCL = -2.0f * LOG2E;
    v2f av[16];                                // av[0..7]=lr pairs, av[8..15]=rl pairs
    {
        float s = 0.0f;
        #pragma unroll
        for (int k = 0; k < 8; ++k) {
            v2f arg = Scol[k] * NSCL;
            v2f e;
            e.x = EXP2F(arg.x);
            e.y = EXP2F(arg.y);
            av[k] = e;
            s += e.x + e.y;
        }
        float inv = RCPF(s);
        #pragma unroll
        for (int k = 0; k < 8; ++k) av[k] = av[k] * inv;
    }
    {
        float s = 0.0f;
        #pragma unroll
        for (int m = 0; m < 8; ++m) {
            v2f sr = (v2f){Srow[2*m], Srow[2*m+1]};
            v2f arg = sr * NSCL;
            v2f e;
            e.x = EXP2F(arg.x);
            e.y = EXP2F(arg.y);
            av[8 + m] = e;
            s += e.x + e.y;
        }
        float inv = RCPF(s);
        #pragma unroll
        for (int m = 0; m < 8; ++m) av[8 + m] = av[8 + m] * inv;
    }

    // ---- out = relu( (x*a) @ dW + db ), packed over output pairs ----
    v2f xa[16];
    #pragma unroll
    for (int m = 0; m < 16; ++m) xa[m] = xv2[m] * av[m];

    const v2f* dW2 = reinterpret_cast<const v2f*>(dW);      // [32][8] pairs
    const v2f* db2 = reinterpret_cast<const v2f*>(db);
    v2f o2[8];
    #pragma unroll
    for (int m = 0; m < 8; ++m) o2[m] = db2[m];
    #pragma unroll
    for (int j = 0; j < 32; ++j) {
        const float xj = xa[j >> 1][j & 1];
        const v2f xj2 = (v2f){xj, xj};
        #pragma unroll
        for (int m = 0; m < 8; ++m)
            o2[m] = fma2(xj2, dW2[j * 8 + m], o2[m]);       // pk_fma (1 sgpr-pair)
    }

    float4* op = reinterpret_cast<float4*>(out + (size_t)i * 16);
    #pragma unroll
    for (int t = 0; t < 4; ++t) {
        v2f a0 = __builtin_elementwise_max(o2[2*t+0], (v2f){0.0f, 0.0f});
        v2f a1 = __builtin_elementwise_max(o2[2*t+1], (v2f){0.0f, 0.0f});
        float4 v;
        v.x = a0.x; v.y = a0.y; v.z = a1.x; v.w = a1.y;
        op[t] = v;
    }
}

extern "C" void kernel_launch(void* const* d_in, const int* in_sizes, int n_in,
                              void* d_out, int out_size, void* d_ws, size_t ws_size,
                              hipStream_t stream) {
    const float* x     = (const float*)d_in[0];
    const float* emb_W = (const float*)d_in[1];
    const float* emb_b = (const float*)d_in[2];
    const float* M     = (const float*)d_in[3];
    const float* dW    = (const float*)d_in[4];
    const float* db    = (const float*)d_in[5];
    float* out = (float*)d_out;
    float* C   = (float*)d_ws;          // 4 * 256 floats = 4 KB

    hipLaunchKernelGGL(coattn_setup, dim3(1), dim3(256), 0, stream,
                       emb_W, emb_b, M, C);

    const int B = in_sizes[0] / 32;
    dim3 block(256);
    dim3 grid((B + 255) / 256);
    hipLaunchKernelGGL(coattn_kernel, grid, block, 0, stream,
                       x, C, dW, db, out);
}